// Round 5
// baseline (318.612 us; speedup 1.0000x reference)
//
#include <hip/hip_runtime.h>

#define HW 36864      // 192*192
#define WD 192
#define BB 8
#define CC 10
#define PW 194                          // padded width (1px zero border)
#define PB ((size_t)(PW*PW*16))         // shorts per (array, b)
#define PA ((size_t)BB*PB)              // shorts per array
#define WSW_OFF ((size_t)10*PA)         // bf16 weight sets: 6 sets x 16 n x 160 k
#define NWSW 15360                      // shorts of weight region
// params (fp32): 2 halves x 302 floats, after weights

typedef __attribute__((ext_vector_type(8))) short short8;
typedef __attribute__((ext_vector_type(4))) float f32x4;

__device__ __forceinline__ f32x4 sp4(float x) { return (f32x4){x, x, x, x}; }

__device__ __forceinline__ short f2bf(float v) {
    unsigned u = __float_as_uint(v);
    unsigned r = (u + 0x7fffu + ((u >> 16) & 1u)) >> 16;   // RNE
    return (short)r;
}
__device__ __forceinline__ float b2f(short s) {
    return __uint_as_float(((unsigned)(unsigned short)s) << 16);
}

#define ASYNC16(gp, lp) __builtin_amdgcn_global_load_lds( \
    (const __attribute__((address_space(1))) void*)(gp),  \
    (__attribute__((address_space(3))) void*)(lp), 16, 0, 0)

// store 4 consecutive pixels x 16ch bf16 (c10..15 = 0), per-pixel scale s[i]
__device__ __forceinline__ void store4(short* d, const f32x4* v, f32x4 s) {
    #pragma unroll
    for (int i = 0; i < 4; ++i) {
        short8 lo = { f2bf(v[0][i]*s[i]), f2bf(v[1][i]*s[i]),
                      f2bf(v[2][i]*s[i]), f2bf(v[3][i]*s[i]),
                      f2bf(v[4][i]*s[i]), f2bf(v[5][i]*s[i]),
                      f2bf(v[6][i]*s[i]), f2bf(v[7][i]*s[i]) };
        short8 hi = { f2bf(v[8][i]*s[i]), f2bf(v[9][i]*s[i]), 0,0,0,0,0,0 };
        *(short8*)(d + i*16)     = lo;
        *(short8*)(d + i*16 + 8) = hi;
    }
}

// ---------------------------------------------------------------------------
// prep: grid 896 blocks x 256.
//  blocks [0,288):   group1 — dmap(+store)+softmax, h0 copy, arrays 0..3
//  blocks [288,576): group2 — cmU(+store), arrays 4..7
//  blocks [576,864): group3 — cmL(+store), arrays 8..9
//  blocks [864,896): border zeroing; block 864 also packs weights+params
// ---------------------------------------------------------------------------
__global__ __launch_bounds__(256) void prep_kernel(
    const float* __restrict__ f_nodes, const float* __restrict__ h_nodes,
    const float* __restrict__ p_nodes,
    const float* __restrict__ w_dmap, const float* __restrict__ b_dmap,
    const float* __restrict__ w_cau, const float* __restrict__ b_cau,
    const float* __restrict__ w_cal, const float* __restrict__ b_cal,
    const float* __restrict__ w_decomp, const float* __restrict__ w_cu,
    const float* __restrict__ w_cl,
    const float* __restrict__ g_decomp, const float* __restrict__ be_decomp,
    const float* __restrict__ g_cu, const float* __restrict__ be_cu,
    const float* __restrict__ g_cl, const float* __restrict__ be_cl,
    const float* __restrict__ wg_u, const float* __restrict__ bg_u,
    const float* __restrict__ wc_u, const float* __restrict__ g_u,
    const float* __restrict__ be_u,
    const float* __restrict__ wg_l, const float* __restrict__ bg_l,
    const float* __restrict__ wc_l, const float* __restrict__ g_l,
    const float* __restrict__ be_l,
    float* __restrict__ out, short* __restrict__ ws)
{
    const int gb  = blockIdx.x;
    const int tid = threadIdx.x;
    const size_t O1 = (size_t)3*BB*CC*HW;
    const size_t O2 = O1 + (size_t)BB*3*HW;
    const size_t O3 = O2 + (size_t)BB*HW;

    if (gb >= 864) {               // ---- borders + weights + params
        int gi = (gb - 864)*256 + tid;   // [0, 8192)
        if (gi < 8*772) {
            int b = gi / 772, r = gi - b*772;
            int py, px;
            if      (r < 194) { py = 0;       px = r;       }
            else if (r < 388) { py = 193;     px = r - 194; }
            else if (r < 580) { py = r - 387; px = 0;       }
            else              { py = r - 579; px = 193;     }
            short* wb = ws + (size_t)b*PB + ((size_t)py*PW + px)*16;
            short8 z = (short8){0,0,0,0,0,0,0,0};
            #pragma unroll
            for (int a = 0; a < 10; ++a) {
                *(short8*)(wb + (size_t)a*PA)     = z;
                *(short8*)(wb + (size_t)a*PA + 8) = z;
            }
        }
        if (gb == 864) {
            short* wsW = ws + WSW_OFF;
            for (int i = tid; i < NWSW/2; i += 256) ((int*)wsW)[i] = 0;
            __syncthreads();
            // sets: 0=Wd_f 1=Wd_h 2=WcU_h 3=WcU_p 4=WcL_h 5=WcL_p ; k=kp*16+c
            for (int i = tid; i < 1800; i += 256) {
                int o = i/180, r = i - o*180, ci = r/9, kp = r - ci*9;
                int c  = (ci < 10) ? ci : ci - 10;
                int s2 = (ci < 10) ? 0 : 1;
                wsW[(size_t)s2*2560     + o*160 + kp*16 + c] = f2bf(w_decomp[i]);
                wsW[(size_t)(2+s2)*2560 + o*160 + kp*16 + c] = f2bf(w_cu[i]);
                wsW[(size_t)(4+s2)*2560 + o*160 + kp*16 + c] = f2bf(w_cl[i]);
            }
            float* wsP = (float*)(ws + WSW_OFF + NWSW);
            #pragma unroll
            for (int hf = 0; hf < 2; ++hf) {
                float* P = wsP + hf*302;
                const float* gC  = hf ? g_cl  : g_cu;
                const float* bC  = hf ? be_cl : be_cu;
                const float* gG  = hf ? g_l   : g_u;
                const float* beG = hf ? be_l  : be_u;
                const float* wg  = hf ? wg_l  : wg_u;
                const float* bg  = hf ? bg_l  : bg_u;
                const float* wc  = hf ? wc_l  : wc_u;
                if (tid < 10) {
                    P[tid]    = g_decomp[tid];  P[10+tid] = be_decomp[tid];
                    P[20+tid] = gC[tid];        P[30+tid] = bC[tid];
                    P[40+tid] = gG[tid];        P[50+tid] = beG[tid];
                }
                if (tid < 40) P[60+tid]  = wg[tid];
                if (tid < 2)  P[100+tid] = bg[tid];
                for (int i = tid; i < 200; i += 256) P[102+i] = wc[i];
            }
        }
        return;
    }

    const int grp = gb / 288;                       // 0,1,2
    const int i0  = (gb - grp*288)*256 + tid;       // [0, 73728)
    const int xq  = i0 % 48;
    const int y   = (i0 / 48) % 192;
    const int b   = i0 / 9216;
    const int sp  = y*WD + 4*xq;
    short* wb = ws + (size_t)b*PB + ((size_t)(y+1)*PW + 4*xq + 1)*16;

    if (grp == 0) {
        const float* f1 = f_nodes + ((size_t)(BB   + b))*CC*HW + sp;
        const float* h0 = h_nodes + ((size_t)        b )*CC*HW + sp;
        const float* h1 = h_nodes + ((size_t)(BB   + b))*CC*HW + sp;
        const float* h2 = h_nodes + ((size_t)(2*BB + b))*CC*HW + sp;

        {   // h0 copy
            #pragma unroll
            for (int c = 0; c < 10; ++c)
                *(f32x4*)(out + (size_t)b*CC*HW + (size_t)c*HW + sp) =
                    *(const f32x4*)(h0 + (size_t)c*HW);
        }
        f32x4 fv[10], av[10], bv[10];
        #pragma unroll
        for (int c = 0; c < 10; ++c) {
            fv[c] = *(const f32x4*)(f1 + (size_t)c*HW);
            av[c] = *(const f32x4*)(h1 + (size_t)c*HW);
            bv[c] = *(const f32x4*)(h2 + (size_t)c*HW);
        }
        f32x4 dm[3];
        #pragma unroll
        for (int j = 0; j < 3; ++j) {
            f32x4 s = sp4(b_dmap[j]);
            #pragma unroll
            for (int c = 0; c < 10; ++c) s += sp4(w_dmap[j*30 + c])      * fv[c];
            #pragma unroll
            for (int c = 0; c < 10; ++c) s += sp4(w_dmap[j*30 + 10 + c]) * av[c];
            #pragma unroll
            for (int c = 0; c < 10; ++c) s += sp4(w_dmap[j*30 + 20 + c]) * bv[c];
            dm[j] = s;
            *(f32x4*)(out + O1 + ((size_t)b*3 + j)*HW + sp) = s;
        }
        f32x4 a1, a2;
        #pragma unroll
        for (int i = 0; i < 4; ++i) {
            float m  = fmaxf(dm[0][i], fmaxf(dm[1][i], dm[2][i]));
            float e0 = expf(dm[0][i]-m), e1 = expf(dm[1][i]-m), e2 = expf(dm[2][i]-m);
            float inv = 1.f / (e0 + e1 + e2);
            a1[i] = e1*inv; a2[i] = e2*inv;
        }
        store4(wb + 0*PA, av, sp4(1.f));
        store4(wb + 1*PA, bv, sp4(1.f));
        store4(wb + 2*PA, fv, a1);
        store4(wb + 3*PA, fv, a2);
    } else if (grp == 1) {
        f32x4 su = sp4(b_cau[0]);
        #pragma unroll
        for (int i = 0; i < 4; ++i) {
            const float* p = p_nodes + ((size_t)((1+i)*BB + b))*CC*HW + sp;
            #pragma unroll
            for (int c = 0; c < 10; ++c)
                su += sp4(w_cau[i*10 + c]) * (*(const f32x4*)(p + (size_t)c*HW));
        }
        f32x4 cm;
        #pragma unroll
        for (int i = 0; i < 4; ++i) cm[i] = 1.f / (1.f + expf(-su[i]));
        *(f32x4*)(out + O2 + (size_t)b*HW + sp) = cm;
        #pragma unroll
        for (int i = 0; i < 4; ++i) {
            const float* p = p_nodes + ((size_t)((1+i)*BB + b))*CC*HW + sp;
            f32x4 pv[10];
            #pragma unroll
            for (int c = 0; c < 10; ++c) pv[c] = *(const f32x4*)(p + (size_t)c*HW);
            store4(wb + (size_t)(4+i)*PA, pv, cm);
        }
    } else {
        f32x4 sl = sp4(b_cal[0]);
        #pragma unroll
        for (int i = 0; i < 2; ++i) {
            const float* p = p_nodes + ((size_t)((5+i)*BB + b))*CC*HW + sp;
            #pragma unroll
            for (int c = 0; c < 10; ++c)
                sl += sp4(w_cal[i*10 + c]) * (*(const f32x4*)(p + (size_t)c*HW));
        }
        f32x4 cm;
        #pragma unroll
        for (int i = 0; i < 4; ++i) cm[i] = 1.f / (1.f + expf(-sl[i]));
        *(f32x4*)(out + O3 + (size_t)b*HW + sp) = cm;
        #pragma unroll
        for (int i = 0; i < 2; ++i) {
            const float* p = p_nodes + ((size_t)((5+i)*BB + b))*CC*HW + sp;
            f32x4 pv[10];
            #pragma unroll
            for (int c = 0; c < 10; ++c) pv[c] = *(const f32x4*)(p + (size_t)c*HW);
            store4(wb + (size_t)(8+i)*PA, pv, cm);
        }
    }
}

// ---------------------------------------------------------------------------
// half_kernel: both halves (z 0..7 upper, 8..15 lower). 16x16 px tile/block.
// R5: dedicated sMsg (no aliasing), plain launch_bounds (no VGPR cap).
// Weights/params read from ws (prep-packed, global/L2-cached B-fragments).
// ---------------------------------------------------------------------------
__device__ __forceinline__ void dma_tile(short* lds, const short* g,
                                         int tid, int y0, int x0)
{
    #pragma unroll
    for (int r = 0; r < 3; ++r) {
        int idx = r*256 + tid;
        int row = idx / 36;               // 36 chunks (576 B) per tile row
        int col = idx - row*36;
        size_t go = (idx < 648) ? (((size_t)(y0+row)*PW + x0)*16 + (size_t)col*8)
                                : (size_t)0;
        ASYNC16(g + go, lds + (size_t)idx*8);
    }
}

__global__ __launch_bounds__(256) void half_kernel(
    const short* __restrict__ ws, float* __restrict__ out)
{
    __shared__ __align__(16) short sTh[6144];
    __shared__ __align__(16) short sTp0[6144];
    __shared__ __align__(16) short sTp1[6144];
    __shared__ float sMsg[256*13];
    __shared__ float sPar[302];

    const int tid  = threadIdx.x;
    const int lane = tid & 63;
    const int w    = tid >> 6;
    const int g    = lane >> 4;
    const int n    = lane & 15;
    const int half = blockIdx.z >> 3;
    const int b    = blockIdx.z & 7;
    const int x0   = blockIdx.x*16, y0 = blockIdx.y*16;
    const int nparts = half ? 2 : 4;

    const short* hArr  = ws + (size_t)half*PA       + (size_t)b*PB;
    const short* fArr  = ws + (size_t)(2+half)*PA   + (size_t)b*PB;
    const short* pArr0 = ws + (size_t)(4+4*half)*PA + (size_t)b*PB;
    const short* wsW   = ws + WSW_OFF;
    const float* wsP   = (const float*)(ws + WSW_OFF + NWSW) + half*302;

    dma_tile(sTh,  hArr,  tid, y0, x0);
    dma_tile(sTp0, fArr,  tid, y0, x0);
    dma_tile(sTp1, pArr0, tid, y0, x0);

    for (int i = tid; i < 302; i += 256) sPar[i] = wsP[i];

    // A-fragment offsets; K = kpos*16 + c, kpos 9 = dummy (zero weights)
    int aoff[5];
    #pragma unroll
    for (int t5 = 0; t5 < 5; ++t5) {
        int k  = 32*t5 + 8*g;
        int kp = k >> 4, c8 = k & 15;
        if (kp < 9) { int ky = kp/3, kx = kp - ky*3; aoff[t5] = (ky*18 + kx + n)*16 + c8; }
        else        aoff[t5] = 0;
    }
    const int wbase = w*4*288;

    __syncthreads();   // DMAs drained (vmcnt before barrier); sPar visible

    // decomp: conv(f*att, Wd_f) + conv(h, Wd_h); shared accH = conv(h, Wc_h)
    f32x4 accD[4], accH[4];
    #pragma unroll
    for (int mt = 0; mt < 4; ++mt) {
        accD[mt] = (f32x4){0.f,0.f,0.f,0.f};
        accH[mt] = (f32x4){0.f,0.f,0.f,0.f};
    }
    {
        short8 bF[5], bH[5], bCh[5];
        #pragma unroll
        for (int t5 = 0; t5 < 5; ++t5) {
            bF[t5]  = *(const short8*)(wsW + (size_t)0*2560 + n*160 + 32*t5 + 8*g);
            bH[t5]  = *(const short8*)(wsW + (size_t)1*2560 + n*160 + 32*t5 + 8*g);
            bCh[t5] = *(const short8*)(wsW + (size_t)(2+2*half)*2560 + n*160 + 32*t5 + 8*g);
        }
        #pragma unroll
        for (int t5 = 0; t5 < 5; ++t5)
            #pragma unroll
            for (int mt = 0; mt < 4; ++mt) {
                short8 a = *(const short8*)(sTp0 + wbase + mt*288 + aoff[t5]);
                accD[mt] = __builtin_amdgcn_mfma_f32_16x16x32_bf16(a, bF[t5], accD[mt], 0,0,0);
            }
        #pragma unroll
        for (int t5 = 0; t5 < 5; ++t5)
            #pragma unroll
            for (int mt = 0; mt < 4; ++mt) {
                short8 a = *(const short8*)(sTh + wbase + mt*288 + aoff[t5]);
                accD[mt] = __builtin_amdgcn_mfma_f32_16x16x32_bf16(a, bH[t5],  accD[mt], 0,0,0);
                accH[mt] = __builtin_amdgcn_mfma_f32_16x16x32_bf16(a, bCh[t5], accH[mt], 0,0,0);
            }
    }
    const int np = (n < 10) ? n : 9;
    const float gDv = sPar[np],    bDv = sPar[10+np];
    const float gCv = sPar[20+np], bCv = sPar[30+np];
    f32x4 msgf[4];
    #pragma unroll
    for (int mt = 0; mt < 4; ++mt)
        #pragma unroll
        for (int j = 0; j < 4; ++j)
            msgf[mt][j] = fmaxf(fmaf(gDv, accD[mt][j], bDv), 0.f);
    __syncthreads();   // sTp0 consumed

    short8 bCp[5];
    #pragma unroll
    for (int t5 = 0; t5 < 5; ++t5)
        bCp[t5] = *(const short8*)(wsW + (size_t)(3+2*half)*2560 + n*160 + 32*t5 + 8*g);

    // parts, double-buffered
    for (int j = 0; j < nparts; ++j) {
        if (j+1 < nparts)
            dma_tile((j&1) ? sTp1 : sTp0, pArr0 + (size_t)(j+1)*PA, tid, y0, x0);
        const short* cur = (j&1) ? sTp0 : sTp1;
        f32x4 acc[4];
        #pragma unroll
        for (int mt = 0; mt < 4; ++mt) acc[mt] = (f32x4){0.f,0.f,0.f,0.f};
        #pragma unroll
        for (int t5 = 0; t5 < 5; ++t5)
            #pragma unroll
            for (int mt = 0; mt < 4; ++mt) {
                short8 a = *(const short8*)(cur + wbase + mt*288 + aoff[t5]);
                acc[mt] = __builtin_amdgcn_mfma_f32_16x16x32_bf16(a, bCp[t5], acc[mt], 0,0,0);
            }
        #pragma unroll
        for (int mt = 0; mt < 4; ++mt)
            #pragma unroll
            for (int jj = 0; jj < 4; ++jj)
                msgf[mt][jj] += fmaxf(fmaf(gCv, accH[mt][jj] + acc[mt][jj], bCv), 0.f);
        __syncthreads();
    }

    // transpose msg to [pixel][ch] (dedicated sMsg)
    if (n < 10) {
        #pragma unroll
        for (int mt = 0; mt < 4; ++mt)
            #pragma unroll
            for (int r2 = 0; r2 < 4; ++r2)
                sMsg[((4*w + mt)*16 + 4*g + r2)*13 + n] = msgf[mt][r2];
    }
    __syncthreads();

    // pointwise ConvGRU epilogue (fp32)
    {
        int row = tid >> 4, xx = tid & 15;
        int gy = y0 + row, gx = x0 + xx;
        float msg[10], hc[10];
        #pragma unroll
        for (int c = 0; c < 10; ++c) msg[c] = sMsg[tid*13 + c];
        #pragma unroll
        for (int c = 0; c < 10; ++c) hc[c] = b2f(sTh[((row+1)*18 + (xx+1))*16 + c]);

        float g0 = sPar[100], g1 = sPar[101];
        #pragma unroll
        for (int c = 0; c < 10; ++c) {
            g0 = fmaf(sPar[60+c], msg[c], g0);
            g1 = fmaf(sPar[80+c], msg[c], g1);
        }
        #pragma unroll
        for (int c = 0; c < 10; ++c) {
            g0 = fmaf(sPar[70+c], hc[c], g0);
            g1 = fmaf(sPar[90+c], hc[c], g1);
        }
        float r = 1.f / (1.f + expf(-g0));
        float u = 1.f / (1.f + expf(-g1));

        float* op = out + (size_t)(1+half)*BB*CC*HW + (size_t)b*CC*HW + gy*WD + gx;
        #pragma unroll
        for (int o = 0; o < 10; ++o) {
            float s = 0.f;
            const float* wr = &sPar[102 + o*20];
            #pragma unroll
            for (int c = 0; c < 10; ++c) s = fmaf(wr[c], msg[c], s);
            #pragma unroll
            for (int c = 0; c < 10; ++c) s = fmaf(wr[10+c], r*hc[c], s);
            s = fmaf(sPar[40+o], s, sPar[50+o]);
            s = (s > 0.f) ? s : 0.01f*s;
            op[(size_t)o*HW] = (1.f - u)*hc[o] + u*s;
        }
    }
}

// ---------------------------------------------------------------------------
extern "C" void kernel_launch(void* const* d_in, const int* in_sizes, int n_in,
                              void* d_out, int out_size, void* d_ws, size_t ws_size,
                              hipStream_t stream)
{
    const float* f_nodes = (const float*)d_in[0];
    const float* h_nodes = (const float*)d_in[1];
    const float* p_nodes = (const float*)d_in[2];
    const float* w_dmap   = (const float*)d_in[4];
    const float* b_dmap   = (const float*)d_in[5];
    const float* w_decomp = (const float*)d_in[6];
    const float* g_decomp = (const float*)d_in[7];
    const float* be_decomp= (const float*)d_in[8];
    const float* w_cau    = (const float*)d_in[9];
    const float* b_cau    = (const float*)d_in[10];
    const float* w_cal    = (const float*)d_in[11];
    const float* b_cal    = (const float*)d_in[12];
    const float* w_cu     = (const float*)d_in[13];
    const float* g_cu     = (const float*)d_in[14];
    const float* be_cu    = (const float*)d_in[15];
    const float* w_cl     = (const float*)d_in[16];
    const float* g_cl     = (const float*)d_in[17];
    const float* be_cl    = (const float*)d_in[18];
    const float* wg_u     = (const float*)d_in[19];
    const float* bg_u     = (const float*)d_in[20];
    const float* wc_u     = (const float*)d_in[21];
    const float* g_u      = (const float*)d_in[22];
    const float* be_u     = (const float*)d_in[23];
    const float* wg_l     = (const float*)d_in[24];
    const float* bg_l     = (const float*)d_in[25];
    const float* wc_l     = (const float*)d_in[26];
    const float* g_l      = (const float*)d_in[27];
    const float* be_l     = (const float*)d_in[28];

    float* out = (float*)d_out;
    short* ws  = (short*)d_ws;

    prep_kernel<<<dim3(896), dim3(256), 0, stream>>>(
        f_nodes, h_nodes, p_nodes, w_dmap, b_dmap,
        w_cau, b_cau, w_cal, b_cal,
        w_decomp, w_cu, w_cl,
        g_decomp, be_decomp, g_cu, be_cu, g_cl, be_cl,
        wg_u, bg_u, wc_u, g_u, be_u,
        wg_l, bg_l, wc_l, g_l, be_l,
        out, ws);

    half_kernel<<<dim3(WD/16, WD/16, 16), dim3(256), 0, stream>>>(ws, out);
}